// Round 1
// 88.707 us; speedup vs baseline: 1.0229x; 1.0229x over previous
//
#include <hip/hip_runtime.h>

// RankingLoss via bucket-ordering:
//   mask[i,j] = t[j] < t[i] is a sorted-prefix once data is ordered by target.
//   Bucket-scatter (4096 value-monotone bins) gives: for a block of RT consecutive
//   ordered rows, j < B[b_lo] qualifies for ALL rows (no compare, no ballot: 3 VALU/pair),
//   j >= B[b_hi+1] qualifies for none (skipped), and only the tiny band in between
//   needs the value-compare + ballot path. Ties are exact: equal t -> equal bucket,
//   band uses strict value compare. Work: N^2/2 pairs at 3 ops vs N^2 at ~10.

constexpr float MARGIN = 0.1f;
constexpr int NBINS  = 4096;
constexpr int RT     = 16;    // rows per block (consecutive sorted positions)
constexpr int T      = 256;   // threads per block
constexpr int NSLOTS = 256;   // partial-sum slots (atomic spread)

__device__ __forceinline__ int bin_of(float t) {
    int b = (int)(t * (float)NBINS);   // monotone in t; equal t -> equal bin
    b = b < 0 ? 0 : b;
    b = b > NBINS - 1 ? NBINS - 1 : b;
    return b;
}

__global__ __launch_bounds__(256) void zero_ws(int* __restrict__ hist,
                                               float* __restrict__ partials) {
    int i = blockIdx.x * 256 + (int)threadIdx.x;
    if (i < NBINS) hist[i] = 0;
    int j = i - NBINS;
    if (j >= 0 && j < NSLOTS) partials[j] = 0.f;
}

__global__ __launch_bounds__(256) void hist_k(const float* __restrict__ target,
                                              int* __restrict__ hist, int n) {
    int i = blockIdx.x * 256 + (int)threadIdx.x;
    if (i < n) atomicAdd(&hist[bin_of(target[i])], 1);
}

__global__ __launch_bounds__(1024) void scan_k(const int* __restrict__ hist,
                                               int* __restrict__ B,
                                               int* __restrict__ cur) {
    __shared__ int part[1024];
    const int t = (int)threadIdx.x;
    int h0 = hist[4 * t + 0], h1 = hist[4 * t + 1];
    int h2 = hist[4 * t + 2], h3 = hist[4 * t + 3];
    int tot = h0 + h1 + h2 + h3;
    part[t] = tot;
    __syncthreads();
    for (int off = 1; off < 1024; off <<= 1) {     // Hillis-Steele inclusive scan
        int v = (t >= off) ? part[t - off] : 0;
        __syncthreads();
        part[t] += v;
        __syncthreads();
    }
    int excl = part[t] - tot;
    int b0 = excl, b1 = b0 + h0, b2 = b1 + h1, b3 = b2 + h2;
    B[4 * t + 0] = b0; B[4 * t + 1] = b1; B[4 * t + 2] = b2; B[4 * t + 3] = b3;
    cur[4 * t + 0] = b0; cur[4 * t + 1] = b1; cur[4 * t + 2] = b2; cur[4 * t + 3] = b3;
    if (t == 1023) B[4096] = part[1023];           // == n
}

__global__ __launch_bounds__(256) void scatter_k(const float* __restrict__ pred,
                                                 const float* __restrict__ target,
                                                 float* __restrict__ ts,
                                                 float* __restrict__ ps,
                                                 int* __restrict__ cur, int n) {
    int i = blockIdx.x * 256 + (int)threadIdx.x;
    if (i < n) {
        float t = target[i], p = pred[i];
        int pos = atomicAdd(&cur[bin_of(t)], 1);   // within-bucket order irrelevant
        ts[pos] = t;
        ps[pos] = p;
    }
}

__global__ __launch_bounds__(T) void rank_sorted(const float* __restrict__ ts,
                                                 const float* __restrict__ ps,
                                                 const int* __restrict__ B,
                                                 float* __restrict__ partials, int n) {
    // heavy-first: block 0 takes the highest sorted positions (longest prefix)
    const int g = (int)gridDim.x - 1 - (int)blockIdx.x;
    const int q = g * RT;

    float ti[RT], ci[RT];
    #pragma unroll
    for (int r = 0; r < RT; ++r) {
        ti[r] = ts[q + r];               // uniform -> scalar loads
        ci[r] = MARGIN - ps[q + r];
    }

    const int Blo = B[bin_of(ti[0])];           // all j < Blo: t_j < every row t
    const int Bhi = B[bin_of(ti[RT - 1]) + 1];  // all j >= Bhi: t_j > every row t
    const int M0 = Blo & ~3;
    int M1 = (Bhi + 3) & ~3;
    if (M1 > n) M1 = n;

    float sum[RT];
    #pragma unroll
    for (int r = 0; r < RT; ++r) sum[r] = 0.f;

    const float4* __restrict__ p4 = (const float4*)ps;
    const float4* __restrict__ t4 = (const float4*)ts;

    // Full region: unconditional hinge, 3 VALU/pair (add, max vs inline 0, add).
    const int f4 = M0 >> 2;
    for (int j = (int)threadIdx.x; j < f4; j += T) {
        const float4 pj = p4[j];
        #pragma unroll
        for (int r = 0; r < RT; ++r) {
            sum[r] += fmaxf(0.f, ci[r] + pj.x);
            sum[r] += fmaxf(0.f, ci[r] + pj.y);
            sum[r] += fmaxf(0.f, ci[r] + pj.z);
            sum[r] += fmaxf(0.f, ci[r] + pj.w);
        }
    }

    // Boundary band [M0, M1): exact value compares (handles ties + rounding slop).
    unsigned int cnt[RT];
    #pragma unroll
    for (int r = 0; r < RT; ++r) cnt[r] = 0u;

    const int m4lo = M0 >> 2, m4hi = M1 >> 2;
    const int iters = (m4hi - m4lo + T - 1) / T;   // block-uniform trip count
    for (int it = 0; it < iters; ++it) {
        const int j = m4lo + it * T + (int)threadIdx.x;
        const bool inb = j < m4hi;
        const int jc = inb ? j : m4lo;
        const float4 tj = t4[jc];
        const float4 pj = p4[jc];
        #pragma unroll
        for (int r = 0; r < RT; ++r) {
            { bool m = inb && (tj.x < ti[r]); float h = fmaxf(0.f, ci[r] + pj.x);
              sum[r] += m ? h : 0.f; cnt[r] += (unsigned)__popcll(__ballot(m)); }
            { bool m = inb && (tj.y < ti[r]); float h = fmaxf(0.f, ci[r] + pj.y);
              sum[r] += m ? h : 0.f; cnt[r] += (unsigned)__popcll(__ballot(m)); }
            { bool m = inb && (tj.z < ti[r]); float h = fmaxf(0.f, ci[r] + pj.z);
              sum[r] += m ? h : 0.f; cnt[r] += (unsigned)__popcll(__ballot(m)); }
            { bool m = inb && (tj.w < ti[r]); float h = fmaxf(0.f, ci[r] + pj.w);
              sum[r] += m ? h : 0.f; cnt[r] += (unsigned)__popcll(__ballot(m)); }
        }
    }

    // Reduce across the block.
    __shared__ float ls[T / 64][RT];
    __shared__ unsigned int lc[T / 64][RT];
    const int lane = (int)threadIdx.x & 63;
    const int wv   = (int)threadIdx.x >> 6;
    #pragma unroll
    for (int r = 0; r < RT; ++r) {
        float s = sum[r];
        #pragma unroll
        for (int off = 32; off > 0; off >>= 1) s += __shfl_down(s, off, 64);
        if (lane == 0) { ls[wv][r] = s; lc[wv][r] = cnt[r]; }
    }
    __syncthreads();

    __shared__ float vrow[RT];
    if ((int)threadIdx.x < RT) {
        float s = 0.f;
        unsigned int c = (unsigned int)M0;     // full region qualifies for every row
        #pragma unroll
        for (int w = 0; w < T / 64; ++w) { s += ls[w][threadIdx.x]; c += lc[w][threadIdx.x]; }
        vrow[threadIdx.x] = (c > 0u) ? s / (float)c : 0.f;
    }
    __syncthreads();
    if (threadIdx.x == 0) {
        float v = 0.f;
        #pragma unroll
        for (int r = 0; r < RT; ++r) v += vrow[r];
        atomicAdd(&partials[blockIdx.x & (NSLOTS - 1)], v);
    }
}

__global__ __launch_bounds__(NSLOTS) void final_k(const float* __restrict__ partials,
                                                  float* __restrict__ out, int n) {
    float s = partials[threadIdx.x];
    #pragma unroll
    for (int off = 32; off > 0; off >>= 1) s += __shfl_down(s, off, 64);
    __shared__ float sd[NSLOTS / 64];
    const int lane = (int)threadIdx.x & 63, wv = (int)threadIdx.x >> 6;
    if (lane == 0) sd[wv] = s;
    __syncthreads();
    if (threadIdx.x == 0) {
        float t = 0.f;
        #pragma unroll
        for (int w = 0; w < NSLOTS / 64; ++w) t += sd[w];
        out[0] = t / (float)n;
    }
}

extern "C" void kernel_launch(void* const* d_in, const int* in_sizes, int n_in,
                              void* d_out, int out_size, void* d_ws, size_t ws_size,
                              hipStream_t stream) {
    const float* pred   = (const float*)d_in[0];
    const float* target = (const float*)d_in[1];
    const int n = in_sizes[0];                 // 16384

    char* w = (char*)d_ws;
    size_t o = 0;
    float* ts       = (float*)(w + o); o += (size_t)n * 4;
    float* ps       = (float*)(w + o); o += (size_t)n * 4;
    int*   hist     = (int*)(w + o);   o += (size_t)NBINS * 4;
    int*   B        = (int*)(w + o);   o += (size_t)(NBINS + 4) * 4;
    int*   cur      = (int*)(w + o);   o += (size_t)NBINS * 4;
    float* partials = (float*)(w + o);

    zero_ws<<<(NBINS + NSLOTS + 255) / 256, 256, 0, stream>>>(hist, partials);
    hist_k<<<(n + 255) / 256, 256, 0, stream>>>(target, hist, n);
    scan_k<<<1, 1024, 0, stream>>>(hist, B, cur);
    scatter_k<<<(n + 255) / 256, 256, 0, stream>>>(pred, target, ts, ps, cur, n);
    rank_sorted<<<n / RT, T, 0, stream>>>(ts, ps, B, partials, n);
    final_k<<<1, NSLOTS, 0, stream>>>(partials, (float*)d_out, n);
}